// Round 2
// baseline (736.964 us; speedup 1.0000x reference)
//
#include <hip/hip_runtime.h>

// Greedy online bipartite matching decode.
// B=4096 rows, V=256 steps, U+1=129 options (col 0 = skip, weight 0).
// One wave64 per row; lane l owns cols l+1 and l+65. First 25 steps are
// provable no-ops (sel=0, weight 0, mask unchanged) -> never read.
// Wave max via DPP (VALU-latency) instead of ds_swizzle shuffles.

template <int CTRL>
__device__ __forceinline__ float maxstep(float v) {
    float t = __int_as_float(__builtin_amdgcn_update_dpp(
        __float_as_int(v), __float_as_int(v), CTRL, 0xF, 0xF, false));
    return fmaxf(v, t);
}

// Full wave64 max; returns the max broadcast to all lanes (via readlane 63).
__device__ __forceinline__ float wave_max_bcast(float v) {
    v = maxstep<0x111>(v);  // row_shr:1
    v = maxstep<0x112>(v);  // row_shr:2
    v = maxstep<0x114>(v);  // row_shr:4
    v = maxstep<0x118>(v);  // row_shr:8  -> lane15 of each row has row max
    v = maxstep<0x142>(v);  // row_bcast:15 -> cross 16-lane rows
    v = maxstep<0x143>(v);  // row_bcast:31 -> lane 63 has wave max
    return __int_as_float(__builtin_amdgcn_readlane(__float_as_int(v), 63));
}

__global__ __launch_bounds__(256, 4) void greedy_match_kernel(
    const float* __restrict__ x,
    float* __restrict__ out,   // [B] = -size, then [B*V] = pi (as float)
    int B)
{
    const int V = 256;
    const int SKIP = 25;
    const int ROWLEN = 129;    // U+1
    const float NEG = -1e30f;

    int gtid = blockIdx.x * blockDim.x + threadIdx.x;
    int w = gtid >> 6;         // wave id = batch row
    int lane = gtid & 63;
    if (w >= B) return;

    const float* base = x + (size_t)w * V * ROWLEN;
    float* out_pi = out + B + (size_t)w * V;

    float acc = 0.0f;          // running matched weight (reference order)
    float pi_val = 0.0f;       // lanes 0..24 keep 0 => skip-phase pi correct
    unsigned int mask = 0;     // bit0: col lane+1 matched; bit1: col lane+65

    // 2-deep row prefetch pipeline
    float w0a = base[(size_t)SKIP * ROWLEN + 1 + lane];
    float w1a = base[(size_t)SKIP * ROWLEN + 65 + lane];
    float w0b = base[(size_t)(SKIP + 1) * ROWLEN + 1 + lane];
    float w1b = base[(size_t)(SKIP + 1) * ROWLEN + 65 + lane];

    for (int t = SKIP; t < V; ++t) {
        int tp = t + 2; if (tp > V - 1) tp = V - 1;
        const float* pp = base + (size_t)tp * ROWLEN;
        float nw0 = pp[1 + lane];
        float nw1 = pp[65 + lane];

        float a0 = (mask & 1u) ? NEG : w0a;
        float a1 = (mask & 2u) ? NEG : w1a;
        float m = fmaxf(fmaxf(a0, a1), 0.0f);   // fold skip (weight 0) in
        float k = wave_max_bcast(m);            // uniform wave max, k >= 0

        int sel = 0;
        if (k > 0.0f) {                          // uniform branch
            // first-occurrence tie-break in column order 1..64 then 65..128
            unsigned long long b0 = __ballot(a0 == k);
            unsigned long long b1 = __ballot(a1 == k);
            sel = b0 ? __ffsll(b0) : (__ffsll(b1) + 64);
        }
        acc += k;                                // chosen weight (0 if skip)

        if (sel == lane + 1)       mask |= 1u;
        else if (sel == lane + 65) mask |= 2u;

        if (lane == (t & 63)) pi_val = (float)sel;
        if ((t & 63) == 63) out_pi[(t & ~63) + lane] = pi_val;

        w0a = w0b; w1a = w1b; w0b = nw0; w1b = nw1;
    }

    if (lane == 0) out[w] = -acc;
}

extern "C" void kernel_launch(void* const* d_in, const int* in_sizes, int n_in,
                              void* d_out, int out_size, void* d_ws, size_t ws_size,
                              hipStream_t stream) {
    const float* x = (const float*)d_in[0];
    const int V = 256, ROWLEN = 129;
    int B = in_sizes[0] / (V * ROWLEN);   // 4096
    float* out = (float*)d_out;

    int threads = 256;                    // 4 waves per block
    int blocks = (B * 64 + threads - 1) / threads;
    greedy_match_kernel<<<blocks, threads, 0, stream>>>(x, out, B);
}

// Round 3
// 696.391 us; speedup vs baseline: 1.0583x; 1.0583x over previous
//
#include <hip/hip_runtime.h>

// Greedy online bipartite matching decode.
// B=4096 rows, V=256 steps, U+1=129 options (col 0 = skip, weight 0).
// One wave64 per row; lane l owns cols l+1 and l+65. First 25 steps are
// provable no-ops (sel=0, weight 0, mask unchanged) -> never read.
// Wave max via DPP; 4-deep row prefetch pipeline for memory-level parallelism.

template <int CTRL>
__device__ __forceinline__ float maxstep(float v) {
    float t = __int_as_float(__builtin_amdgcn_update_dpp(
        __float_as_int(v), __float_as_int(v), CTRL, 0xF, 0xF, false));
    return fmaxf(v, t);
}

// Full wave64 max broadcast to all lanes.
__device__ __forceinline__ float wave_max_bcast(float v) {
    v = maxstep<0x111>(v);  // row_shr:1
    v = maxstep<0x112>(v);  // row_shr:2
    v = maxstep<0x114>(v);  // row_shr:4
    v = maxstep<0x118>(v);  // row_shr:8  -> lane15 of each 16-row has row max
    v = maxstep<0x142>(v);  // row_bcast:15
    v = maxstep<0x143>(v);  // row_bcast:31 -> lane 63 has wave max
    return __int_as_float(__builtin_amdgcn_readlane(__float_as_int(v), 63));
}

__global__ __launch_bounds__(256, 4) void greedy_match_kernel(
    const float* __restrict__ x,
    float* __restrict__ out,   // [B] = -size, then [B*V] = pi (as float)
    int B)
{
    const int V = 256;
    const int SKIP = 25;
    const int ROWLEN = 129;    // U+1
    const float NEG = -1e30f;
    const int DEPTH = 4;       // prefetch pipeline depth (rows)

    int gtid = blockIdx.x * blockDim.x + threadIdx.x;
    int w = gtid >> 6;         // wave id = batch row
    int lane = gtid & 63;
    if (w >= B) return;

    const float* base = x + (size_t)w * V * ROWLEN;
    float* out_pi = out + B + (size_t)w * V;

    float acc = 0.0f;          // running matched weight (reference order)
    float pi_val = 0.0f;       // lanes 0..24 keep 0 => skip-phase pi correct
    unsigned int mask = 0;     // bit0: col lane+1 matched; bit1: col lane+65

    // fill the 4-deep pipeline (rows SKIP .. SKIP+3)
    float p0[DEPTH], p1[DEPTH];
    #pragma unroll
    for (int i = 0; i < DEPTH; ++i) {
        const float* r = base + (size_t)(SKIP + i) * ROWLEN;
        p0[i] = __builtin_nontemporal_load(r + 1 + lane);
        p1[i] = __builtin_nontemporal_load(r + 65 + lane);
    }

    #pragma unroll 4
    for (int t = SKIP; t < V; ++t) {
        int idx = (t - SKIP) & (DEPTH - 1);
        int tp = t + DEPTH; if (tp > V - 1) tp = V - 1;   // tail: redundant re-reads
        const float* pp = base + (size_t)tp * ROWLEN;
        float nw0 = __builtin_nontemporal_load(pp + 1 + lane);
        float nw1 = __builtin_nontemporal_load(pp + 65 + lane);

        float a0 = (mask & 1u) ? NEG : p0[idx];
        float a1 = (mask & 2u) ? NEG : p1[idx];
        float m = fmaxf(fmaxf(a0, a1), 0.0f);   // fold skip (weight 0) in
        float k = wave_max_bcast(m);            // uniform wave max, k >= 0

        int sel = 0;
        if (k > 0.0f) {                          // uniform branch
            // first-occurrence tie-break: cols 1..64 then 65..128
            unsigned long long b0 = __ballot(a0 == k);
            unsigned long long b1 = __ballot(a1 == k);
            sel = b0 ? __ffsll(b0) : (__ffsll(b1) + 64);
        }
        acc += k;                                // chosen weight (0 if skip)

        if (sel == lane + 1)       mask |= 1u;
        else if (sel == lane + 65) mask |= 2u;

        if (lane == (t & 63)) pi_val = (float)sel;
        if ((t & 63) == 63) out_pi[(t & ~63) + lane] = pi_val;

        p0[idx] = nw0; p1[idx] = nw1;
    }

    if (lane == 0) out[w] = -acc;
}

extern "C" void kernel_launch(void* const* d_in, const int* in_sizes, int n_in,
                              void* d_out, int out_size, void* d_ws, size_t ws_size,
                              hipStream_t stream) {
    const float* x = (const float*)d_in[0];
    const int V = 256, ROWLEN = 129;
    int B = in_sizes[0] / (V * ROWLEN);   // 4096
    float* out = (float*)d_out;

    int threads = 256;                    // 4 waves per block
    int blocks = (B * 64 + threads - 1) / threads;
    greedy_match_kernel<<<blocks, threads, 0, stream>>>(x, out, B);
}